// Round 4
// baseline (475.745 us; speedup 1.0000x reference)
//
#include <hip/hip_runtime.h>
#include <hip/hip_bf16.h>
#include <math.h>

#define B_   32
#define S_   512
#define SxS  (S_ * S_)
#define LOG2E 1.4426950408889634f

using frag_ab = __attribute__((ext_vector_type(8))) short;   // 8 bf16 = 4 VGPR
using frag_cd = __attribute__((ext_vector_type(4))) float;   // 4 fp32 acc

__device__ inline short f2bf(float x) {
    __hip_bfloat16 h = __float2bfloat16(x);
    return *reinterpret_cast<short*>(&h);
}
__device__ inline float bf2f(short s) {
    __hip_bfloat16 h = *reinterpret_cast<__hip_bfloat16*>(&s);
    return __bfloat162float(h);
}
__device__ __forceinline__ int swz(int r) { return (r ^ (r >> 3)) & 7; }

// async global->LDS, 16B per lane. LDS dest must be wave-uniform base.
__device__ __forceinline__ void async16(const short* g, short* l) {
    __builtin_amdgcn_global_load_lds(
        (const __attribute__((address_space(1))) void*)g,
        (__attribute__((address_space(3))) void*)l,
        16, 0, 0);
}

// ---------------------------------------------------------------------------
// k_prep (unchanged, verified): reads A/B fp32 once. Produces:
//   1) PA/PB: packed hi/lo bf16 planes for the e-GEMM (PA pre-scaled LOG2E).
//   2) Va/Vb: bf16 transposed V-planes Vp[d][64-i group][chunk^(d&7)].
// ---------------------------------------------------------------------------
__global__ __launch_bounds__(256) void k_prep(const float* __restrict__ A,
                                              const float* __restrict__ Bm,
                                              short* __restrict__ PA,
                                              short* __restrict__ PB,
                                              short* __restrict__ Va,
                                              short* __restrict__ Vb)
{
    const int z   = blockIdx.z;          // 0..63
    const int b   = z & 31;
    const int isB = z >> 5;
    const float* X = (isB ? Bm : A) + (size_t)b * SxS;
    short* P  = (isB ? PB : PA) + (size_t)b * (S_ * 1024);
    short* Vp = (isB ? Vb : Va) + (size_t)b * SxS;
    const float scale = isB ? 1.0f : LOG2E;

    const int i0 = blockIdx.y * 64, d0 = blockIdx.x * 64;

    __shared__ short T[64][72];

    const int sl = threadIdx.x & 7;
    const int il = threadIdx.x >> 3;

    #pragma unroll
    for (int p = 0; p < 2; ++p) {
        const int i    = il + 32 * p;
        const int rowg = i0 + i;
        const float* src = X + (size_t)rowg * S_ + d0 + sl * 8;
        const float4 v0 = *(const float4*)(src);
        const float4 v1 = *(const float4*)(src + 4);

        T[sl * 8 + 0][i] = f2bf(v0.x); T[sl * 8 + 1][i] = f2bf(v0.y);
        T[sl * 8 + 2][i] = f2bf(v0.z); T[sl * 8 + 3][i] = f2bf(v0.w);
        T[sl * 8 + 4][i] = f2bf(v1.x); T[sl * 8 + 5][i] = f2bf(v1.y);
        T[sl * 8 + 6][i] = f2bf(v1.z); T[sl * 8 + 7][i] = f2bf(v1.w);

        const float xs[8] = {v0.x, v0.y, v0.z, v0.w, v1.x, v1.y, v1.z, v1.w};
        frag_ab hi, lo;
        #pragma unroll
        for (int j = 0; j < 8; ++j) {
            const float x = xs[j] * scale;
            const short h = f2bf(x);
            hi[j] = h;
            lo[j] = f2bf(x - bf2f(h));
        }
        const int W = (d0 >> 5) + (sl >> 2);
        const int q = sl & 3;
        short* base = P + (size_t)rowg * 1024 + W * 64;
        *(frag_ab*)(base + (((2 * q)     ^ (rowg & 7)) * 8)) = hi;
        *(frag_ab*)(base + (((2 * q + 1) ^ (rowg & 7)) * 8)) = lo;
    }
    __syncthreads();

    const int pc = threadIdx.x & 7, dl = threadIdx.x >> 3;
    #pragma unroll
    for (int p = 0; p < 2; ++p) {
        const int d  = dl + 32 * p;
        const int dg = d0 + d;
        frag_ab t = *(const frag_ab*)&T[d][pc * 8];
        *(frag_ab*)(Vp + (size_t)dg * 512 + i0 + ((pc ^ (dg & 7)) * 8)) = t;
    }
}

// ---------------------------------------------------------------------------
// e' = (LOG2E*A)·B^T via hi/lo bf16 MFMA (unchanged, verified). Writes E.
// ---------------------------------------------------------------------------
__global__ __launch_bounds__(256) void k_gemm_e(const short* __restrict__ PA,
                                                const short* __restrict__ PB,
                                                float* __restrict__ E)
{
    const int lin     = blockIdx.x + (blockIdx.y << 2) + (blockIdx.z << 4);
    const int logical = ((lin & 7) << 6) + (lin >> 3);
    const int b  = logical >> 4;
    const int i0 = ((logical >> 2) & 3) * 128;
    const int j0 = (logical & 3) * 128;

    const short* Ab = PA + (size_t)b * (S_ * 1024);
    const short* Bb = PB + (size_t)b * (S_ * 1024);
    float* Eb = E + (size_t)b * SxS;

    __shared__ __align__(16) short As[128][64];
    __shared__ __align__(16) short Bs[128][64];

    const int tid  = threadIdx.x;
    const int wave = tid >> 6, lane = tid & 63;
    const int wr   = wave >> 1, wc = wave & 1;
    const int q    = lane >> 4, m = lane & 15;
    const int srow = lane >> 3, schunk = lane & 7;

    frag_cd zero = {0.f, 0.f, 0.f, 0.f};
    frag_cd acc[4][4];
    #pragma unroll
    for (int i = 0; i < 4; ++i)
        #pragma unroll
        for (int j = 0; j < 4; ++j) acc[i][j] = zero;

    for (int k0 = 0; k0 < S_; k0 += 32) {
        const int W = k0 >> 5;
        __syncthreads();
        #pragma unroll
        for (int p = 0; p < 4; ++p) {
            const int seg    = wave * 4 + p;
            const int rowg_a = i0 + seg * 8 + srow;
            const int rowg_b = j0 + seg * 8 + srow;
            async16(Ab + (size_t)rowg_a * 1024 + W * 64 + schunk * 8, &As[seg * 8][0]);
            async16(Bb + (size_t)rowg_b * 1024 + W * 64 + schunk * 8, &Bs[seg * 8][0]);
        }
        __syncthreads();

        frag_ab ah[4], al[4], bh[4], bl[4];
        #pragma unroll
        for (int t = 0; t < 4; ++t) {
            const int ra = wr * 64 + t * 16 + m;
            const int rb = wc * 64 + t * 16 + m;
            ah[t] = *(const frag_ab*)&As[ra][((2 * q)     ^ (ra & 7)) * 8];
            al[t] = *(const frag_ab*)&As[ra][((2 * q + 1) ^ (ra & 7)) * 8];
            bh[t] = *(const frag_ab*)&Bs[rb][((2 * q)     ^ (rb & 7)) * 8];
            bl[t] = *(const frag_ab*)&Bs[rb][((2 * q + 1) ^ (rb & 7)) * 8];
        }
        #pragma unroll
        for (int mt = 0; mt < 4; ++mt)
            #pragma unroll
            for (int nt = 0; nt < 4; ++nt) {
                acc[mt][nt] = __builtin_amdgcn_mfma_f32_16x16x32_bf16(ah[mt], bh[nt], acc[mt][nt], 0, 0, 0);
                acc[mt][nt] = __builtin_amdgcn_mfma_f32_16x16x32_bf16(ah[mt], bl[nt], acc[mt][nt], 0, 0, 0);
                acc[mt][nt] = __builtin_amdgcn_mfma_f32_16x16x32_bf16(al[mt], bh[nt], acc[mt][nt], 0, 0, 0);
            }
    }

    #pragma unroll
    for (int mt = 0; mt < 4; ++mt)
        #pragma unroll
        for (int nt = 0; nt < 4; ++nt) {
            const int rb  = i0 + wr * 64 + mt * 16 + q * 4;
            const int col = j0 + wc * 64 + nt * 16 + m;
            Eb[(size_t)(rb + 0) * S_ + col] = acc[mt][nt][0];
            Eb[(size_t)(rb + 1) * S_ + col] = acc[mt][nt][1];
            Eb[(size_t)(rb + 2) * S_ + col] = acc[mt][nt][2];
            Eb[(size_t)(rb + 3) * S_ + col] = acc[mt][nt][3];
        }
}

// ---------------------------------------------------------------------------
// k_rstats: per-row max and 1/sum(exp2) over E (exp2 domain). 1 wave/row.
// ---------------------------------------------------------------------------
__global__ __launch_bounds__(256) void k_rstats(const float* __restrict__ E,
                                                float* __restrict__ rmax,
                                                float* __restrict__ rinv)
{
    const int row  = blockIdx.x * 4 + (threadIdx.x >> 6);
    const int lane = threadIdx.x & 63;
    const float* er = E + (size_t)row * S_;

    float4 v0 = *(const float4*)(er + lane * 4);
    float4 v1 = *(const float4*)(er + 256 + lane * 4);

    float m = fmaxf(fmaxf(fmaxf(v0.x, v0.y), fmaxf(v0.z, v0.w)),
                    fmaxf(fmaxf(v1.x, v1.y), fmaxf(v1.z, v1.w)));
    #pragma unroll
    for (int off = 32; off >= 1; off >>= 1)
        m = fmaxf(m, __shfl_xor(m, off));

    float s = exp2f(v0.x - m) + exp2f(v0.y - m)
            + exp2f(v0.z - m) + exp2f(v0.w - m)
            + exp2f(v1.x - m) + exp2f(v1.y - m)
            + exp2f(v1.z - m) + exp2f(v1.w - m);
    #pragma unroll
    for (int off = 32; off >= 1; off >>= 1)
        s += __shfl_xor(s, off);

    if (lane == 0) { rmax[row] = m; rinv[row] = 1.0f / s; }
}

// ---------------------------------------------------------------------------
// k_cstats: per-col max and 1/sum(exp2) over E. Block = (b, 64-col strip),
// 256 threads: thread = 16-row bundle x 8 cols, LDS tree over 32 bundles.
// ---------------------------------------------------------------------------
__global__ __launch_bounds__(256) void k_cstats(const float* __restrict__ E,
                                                float* __restrict__ cmax,
                                                float* __restrict__ cinv)
{
    const int b  = blockIdx.x >> 3;
    const int s0 = (blockIdx.x & 7) * 64;
    const float* Eb = E + (size_t)b * SxS;

    __shared__ float scr[32][64];
    __shared__ float mS[64];

    const int tid = threadIdx.x;
    const int ib  = tid >> 3;          // 0..31, rows ib*16..+16
    const int sub = tid & 7;           // cols s0 + sub*8..+8

    float pm[8];
    #pragma unroll
    for (int c = 0; c < 8; ++c) pm[c] = -INFINITY;
    for (int ii = 0; ii < 16; ++ii) {
        const float* p = Eb + (size_t)(ib * 16 + ii) * S_ + s0 + sub * 8;
        const float4 u  = *(const float4*)p;
        const float4 u2 = *(const float4*)(p + 4);
        pm[0] = fmaxf(pm[0], u.x);  pm[1] = fmaxf(pm[1], u.y);
        pm[2] = fmaxf(pm[2], u.z);  pm[3] = fmaxf(pm[3], u.w);
        pm[4] = fmaxf(pm[4], u2.x); pm[5] = fmaxf(pm[5], u2.y);
        pm[6] = fmaxf(pm[6], u2.z); pm[7] = fmaxf(pm[7], u2.w);
    }
    #pragma unroll
    for (int c = 0; c < 8; ++c) scr[ib][sub * 8 + c] = pm[c];
    __syncthreads();
    if (tid < 64) {
        float v = scr[0][tid];
        #pragma unroll
        for (int k = 1; k < 32; ++k) v = fmaxf(v, scr[k][tid]);
        mS[tid] = v;
        cmax[b * S_ + s0 + tid] = v;
    }
    __syncthreads();

    float ps[8];
    #pragma unroll
    for (int c = 0; c < 8; ++c) ps[c] = 0.f;
    for (int ii = 0; ii < 16; ++ii) {
        const float* p = Eb + (size_t)(ib * 16 + ii) * S_ + s0 + sub * 8;
        const float4 u  = *(const float4*)p;
        const float4 u2 = *(const float4*)(p + 4);
        const float xs[8] = {u.x, u.y, u.z, u.w, u2.x, u2.y, u2.z, u2.w};
        #pragma unroll
        for (int c = 0; c < 8; ++c) ps[c] += exp2f(xs[c] - mS[sub * 8 + c]);
    }
    __syncthreads();
    #pragma unroll
    for (int c = 0; c < 8; ++c) scr[ib][sub * 8 + c] = ps[c];
    __syncthreads();
    if (tid < 64) {
        float v = 0.f;
        #pragma unroll
        for (int k = 0; k < 32; ++k) v += scr[k][tid];
        cinv[b * S_ + s0 + tid] = 1.0f / v;
    }
}

// ---------------------------------------------------------------------------
// k_pv: C[32 out-rows][256 d-cols] = P · V with P built in LDS from E + stats
// (one exp pass, no max pass). LDS 64 KB -> 2 blocks/CU. 256 thr, 4 waves.
// Grid 2048: (side, b, row-strip 0..15, d-half 0..1), XCD-swizzled.
// ---------------------------------------------------------------------------
__global__ __launch_bounds__(256) void k_pv(const float* __restrict__ E,
                                            const float* __restrict__ rmx_,
                                            const float* __restrict__ rin_,
                                            const float* __restrict__ cmx_,
                                            const float* __restrict__ cin_,
                                            const short* __restrict__ Va,
                                            const short* __restrict__ Vb,
                                            const float* __restrict__ A,
                                            const float* __restrict__ Bm,
                                            float* __restrict__ Ma,
                                            float* __restrict__ Mb)
{
    const int lin = blockIdx.x;                       // 0..2047
    const int wg  = ((lin & 7) << 8) | (lin >> 3);    // bijective XCD swizzle
    const int side = wg >> 10;
    const int b    = (wg >> 5) & 31;
    const int rs   = (wg >> 1) & 15;                  // 32-row strip
    const int dh   = wg & 1;                          // 256-col half
    const int s0   = rs * 32;

    const float* Eb  = E + (size_t)b * SxS;
    const float* pmx = (side ? cmx_ : rmx_) + b * S_;
    const float* piv = (side ? cin_ : rin_) + b * S_;
    const short* Vg  = (side ? Va : Vb) + (size_t)b * SxS;
    const float* Xb  = (side ? Bm : A) + (size_t)b * SxS;
    float* Ob = (side ? Mb : Ma) + (size_t)b * S_ * 2048;

    __shared__ __align__(16) short Pl[32][512];   // 32 KB
    __shared__ __align__(16) short Vs[256][64];   // 32 KB
    __shared__ float riS[32];

    const int tid = threadIdx.x;
    const int wv  = tid >> 6, lane = tid & 63;
    const int q   = lane >> 4, m = lane & 15;

    if (tid < 32) riS[tid] = piv[s0 + tid];

    // ---------------- Phase A: build P strip in LDS (one exp pass) --------
    if (side == 0) {
        // rows s0..s0+32 of E, full 512 cols. thread: row rl = tid>>3, 64 cols.
        const int rl = tid >> 3, sub = tid & 7;
        const float mx = pmx[s0 + rl];
        const float* er = Eb + (size_t)(s0 + rl) * S_;
        const int sl = (sub ^ swz(rl)) * 8;
        #pragma unroll
        for (int fi = 0; fi < 8; ++fi) {
            const float* p = er + sub * 8 + fi * 64;
            const float4 u  = *(const float4*)p;
            const float4 u2 = *(const float4*)(p + 4);
            const float xs[8] = {u.x, u.y, u.z, u.w, u2.x, u2.y, u2.z, u2.w};
            frag_ab pb;
            #pragma unroll
            for (int j = 0; j < 8; ++j) pb[j] = f2bf(exp2f(xs[j] - mx));
            *(frag_ab*)&Pl[rl][fi * 64 + sl] = pb;
        }
    } else {
        // cols s0..s0+32 of E, all 512 rows (K = i). thread: 8-row bundle x 8 cols.
        const int ib = tid >> 2, cs = tid & 3;        // ib 0..63, cols cs*8..+8
        float mloc[8];
        #pragma unroll
        for (int c = 0; c < 8; ++c) mloc[c] = pmx[s0 + cs * 8 + c];
        frag_ab pb[8];
        #pragma unroll
        for (int ii = 0; ii < 8; ++ii) {
            const float* p = Eb + (size_t)(ib * 8 + ii) * S_ + s0 + cs * 8;
            const float4 u  = *(const float4*)p;
            const float4 u2 = *(const float4*)(p + 4);
            const float xs[8] = {u.x, u.y, u.z, u.w, u2.x, u2.y, u2.z, u2.w};
            #pragma unroll
            for (int c = 0; c < 8; ++c)
                pb[c][ii] = f2bf(exp2f(xs[c] - mloc[c]));
        }
        #pragma unroll
        for (int c = 0; c < 8; ++c) {
            const int cl = cs * 8 + c;
            *(frag_ab*)&Pl[cl][((ib ^ swz(cl)) & 63) * 8
                               + (ib & ~7) * 0] = pb[c];   // (ib^s)<=63 since s<8
        }
    }

    // ---------------- Phase B: C = P · V ----------------------------------
    frag_cd zero = {0.f, 0.f, 0.f, 0.f};
    frag_cd acc[2][4];
    #pragma unroll
    for (int i = 0; i < 2; ++i)
        #pragma unroll
        for (int j = 0; j < 4; ++j) acc[i][j] = zero;

    for (int k0 = 0; k0 < S_; k0 += 64) {
        __syncthreads();                 // Pl ready (first iter) / Vs free
        #pragma unroll
        for (int p = 0; p < 8; ++p) {
            const int seg = p * 32 + wv * 8;              // wave-uniform
            const int d   = dh * 256 + seg + (lane >> 3);
            async16(Vg + (size_t)d * 512 + k0 + (lane & 7) * 8, &Vs[seg][0]);
        }
        __syncthreads();                 // drain

        #pragma unroll
        for (int kk = 0; kk < 2; ++kk) {
            frag_ab af[2], bf[4];
            #pragma unroll
            for (int t = 0; t < 2; ++t) {
                const int ra = t * 16 + m;
                af[t] = *(const frag_ab*)&Pl[ra][k0 + (((kk * 4 + q) ^ swz(ra)) * 8)];
            }
            #pragma unroll
            for (int t = 0; t < 4; ++t) {
                const int dl = wv * 64 + t * 16 + m;      // local d (0..255)
                bf[t] = *(const frag_ab*)&Vs[dl][(((kk * 4 + q) ^ (dl & 7)) * 8)];
            }
            #pragma unroll
            for (int mt = 0; mt < 2; ++mt)
                #pragma unroll
                for (int nt = 0; nt < 4; ++nt)
                    acc[mt][nt] = __builtin_amdgcn_mfma_f32_16x16x32_bf16(af[mt], bf[nt], acc[mt][nt], 0, 0, 0);
        }
    }

    // ---------------- Epilogue --------------------------------------------
    #pragma unroll
    for (int mt = 0; mt < 2; ++mt)
        #pragma unroll
        for (int nt = 0; nt < 4; ++nt) {
            const int colg = dh * 256 + wv * 64 + nt * 16 + m;
            #pragma unroll
            for (int rr = 0; rr < 4; ++rr) {
                const int rl   = mt * 16 + q * 4 + rr;
                const int rowg = s0 + rl;
                const float at = acc[mt][nt][rr] * riS[rl];
                const float xv = Xb[(size_t)rowg * S_ + colg];
                float* o = Ob + (size_t)rowg * 2048 + colg;
                o[0]    = xv;
                o[512]  = at;
                o[1024] = xv - at;
                o[1536] = xv * at;
            }
        }
}

// ---------------------------------------------------------------------------
extern "C" void kernel_launch(void* const* d_in, const int* in_sizes, int n_in,
                              void* d_out, int out_size, void* d_ws, size_t ws_size,
                              hipStream_t stream)
{
    const float* A  = (const float*)d_in[0];   // a_bar [32,512,512]
    const float* Bm = (const float*)d_in[1];   // b_bar [32,512,512]
    float* Ma = (float*)d_out;                             // [32,512,2048]
    float* Mb = Ma + (size_t)B_ * S_ * 2048;               // [32,512,2048]

    // ws: E 33.5 MB + Va/Vb 16.8 MB each + stats ~0.26 MB
    float* E    = (float*)d_ws;
    short* Va   = (short*)(E + (size_t)B_ * SxS);
    short* Vb   = Va + (size_t)B_ * SxS;
    float* rmax = (float*)(Vb + (size_t)B_ * SxS);
    float* rinv = rmax + B_ * S_;
    float* cmax = rinv + B_ * S_;
    float* cinv = cmax + B_ * S_;

    // PA/PB hi/lo planes scratch in the OUTPUT buffer (dead after k_gemm_e).
    short* PA = (short*)d_out;
    short* PB = PA + (size_t)B_ * S_ * 1024;

    k_prep  <<<dim3(8, 8, 64),    256, 0, stream>>>(A, Bm, PA, PB, Va, Vb);
    k_gemm_e<<<dim3(4, 4, 32),    256, 0, stream>>>(PA, PB, E);
    k_rstats<<<dim3(B_ * S_ / 4), 256, 0, stream>>>(E, rmax, rinv);
    k_cstats<<<dim3(B_ * 8),      256, 0, stream>>>(E, cmax, cinv);
    k_pv    <<<dim3(2048),        256, 0, stream>>>(E, rmax, rinv, cmax, cinv,
                                                    Va, Vb, A, Bm, Ma, Mb);
}